// Round 8
// baseline (558.325 us; speedup 1.0000x reference)
//
#include <hip/hip_runtime.h>
#include <hip/hip_bf16.h>
#include <math.h>

typedef __attribute__((ext_vector_type(8))) __bf16 bf16x8;
typedef __attribute__((ext_vector_type(4))) float f32x4;

constexpr float VX_ = 0.2f;
constexpr float VY_ = 0.2f;
constexpr float X_OFF_ = 0.1f;    // VX/2 + 0.0
constexpr float Y_OFF_ = -39.9f;  // VY/2 - 40.0
constexpr float EPS_ = 1e-3f;

#define S1 512               // kA block count
#define MAGICF 0x5CA1AB1Eu   // ab-ready flag value

__device__ __forceinline__ float wave_sum(float v) {
#pragma unroll
  for (int off = 32; off; off >>= 1) v += __shfl_xor(v, off);
  return v;
}

__device__ __forceinline__ ushort bf16bits(float x) {
  __hip_bfloat16 h = __float2bfloat16(x);
  return __builtin_bit_cast(ushort, h);
}

// kA: inlined prep (W->LDS, G' scaled W^T W + wsum) + per-n moments,
// pre-contracted to 2 floats/thread. Block sums -> partials[b*128 + t]
// (t<64: sum x contribution for n=t; t in 64..127: sum x^2 for n=t-64).
__global__ __launch_bounds__(256) void kA_moments(
    const float* __restrict__ feats, const int* __restrict__ npts_arr,
    const int* __restrict__ coors, const float* __restrict__ W,
    float* __restrict__ partials, int P) {
  __shared__ float W_lds[576];
  __shared__ float gws[54];  // G'[45] (off-diag doubled) + wsum[9]
  __shared__ float2 red[4][64];
  const int t = threadIdx.x, lane = t & 63, wv = t >> 6;

  for (int i = t; i < 576; i += 256) W_lds[i] = W[i];
  __syncthreads();
  if (t < 180) {  // G': 45 pairs x 4-way split over o
    const int pr = t >> 2, k = t & 3;
    int c = 0, rem = pr;
    while (rem >= 9 - c) {
      rem -= 9 - c;
      ++c;
    }
    const int c2 = c + rem;
    float s = 0.f;
    for (int o = k * 16; o < k * 16 + 16; ++o)
      s += W_lds[o * 9 + c] * W_lds[o * 9 + c2];
    s += __shfl_xor(s, 1);
    s += __shfl_xor(s, 2);
    if (k == 0) gws[pr] = (c == c2) ? s : 2.f * s;
  } else if (t < 216) {  // wsum: 9 cols x 4-way split
    const int tt = t - 180, c = tt >> 2, k = tt & 3;
    float s = 0.f;
    for (int o = k * 16; o < k * 16 + 16; ++o) s += W_lds[o * 9 + c];
    s += __shfl_xor(s, 1);
    s += __shfl_xor(s, 2);
    if (k == 0) gws[45 + c] = s;
  }
  __syncthreads();
  float g[45], wsv[9];
#pragma unroll
  for (int i = 0; i < 45; ++i) g[i] = gws[i];
#pragma unroll
  for (int i = 0; i < 9; ++i) wsv[i] = gws[45 + i];

  float s1 = 0.f, s2 = 0.f;
  const int nw = S1 * 4;
  int p = blockIdx.x * 4 + wv;
  if (p < P) {
    float4 f =
        *reinterpret_cast<const float4*>(feats + (size_t)p * 256 + lane * 4);
    int np = npts_arr[p];
    int cx = coors[p * 4 + 3], cy = coors[p * 4 + 2];
    while (true) {
      const int p2 = p + nw;
      const bool has2 = p2 < P;
      float4 f2 = make_float4(0.f, 0.f, 0.f, 0.f);
      int np2 = 1, cx2 = 0, cy2 = 0;
      if (has2) {  // prefetch next pillar
        f2 = *reinterpret_cast<const float4*>(feats + (size_t)p2 * 256 +
                                              lane * 4);
        np2 = npts_arr[p2];
        cx2 = coors[p2 * 4 + 3];
        cy2 = coors[p2 * 4 + 2];
      }
      const float ox = (float)cx * VX_ + X_OFF_;
      const float oy = (float)cy * VY_ + Y_OFF_;
      const float inv = 1.f / (float)np;
      const float m0 = wave_sum(f.x) * inv;
      const float m1 = wave_sum(f.y) * inv;
      const float m2 = wave_sum(f.z) * inv;
      const bool valid = lane < np;
      float ft[9] = {f.x,      f.y,      f.z,      f.w,      f.x - m0,
                     f.y - m1, f.z - m2, f.x - ox, f.y - oy};
#pragma unroll
      for (int c = 0; c < 9; ++c) ft[c] = valid ? ft[c] : 0.f;
      int idx = 0;
      float t1 = 0.f, t2 = 0.f;
#pragma unroll
      for (int c = 0; c < 9; ++c) {
        float u = 0.f;
#pragma unroll
        for (int c2 = c; c2 < 9; ++c2) u = fmaf(g[idx++], ft[c2], u);
        t2 = fmaf(ft[c], u, t2);
        t1 = fmaf(ft[c], wsv[c], t1);
      }
      s1 += t1;
      s2 += t2;
      if (!has2) break;
      p = p2;
      f = f2;
      np = np2;
      cx = cx2;
      cy = cy2;
    }
  }
  red[wv][lane] = make_float2(s1, s2);
  __syncthreads();
  if (t < 128) {
    const int n = t & 63, j = t >> 6;
    const float v = (j == 0)
                        ? (red[0][n].x + red[1][n].x + red[2][n].x + red[3][n].x)
                        : (red[0][n].y + red[1][n].y + red[2][n].y + red[3][n].y);
    partials[(size_t)blockIdx.x * 128 + t] = v;  // coalesced, non-atomic
  }
}

// Deterministic stats reduction: partials[S1][128] -> shab (and optionally
// global ab). Identical code on every path => identical FP results.
__device__ __forceinline__ void do_stats(const float* __restrict__ partials,
                                         const float* __restrict__ gamma,
                                         const float* __restrict__ beta,
                                         float* __restrict__ abg,
                                         float2* shab, float* tmp, int P,
                                         int t, bool write_global) {
  const int half = S1 >> 1;
  const int col = t & 127;
  const int b0 = (t < 128) ? 0 : half;
  const int b1 = (t < 128) ? half : S1;
  float s = 0.f;
  for (int b = b0; b < b1; b += 2) {  // coalesced: 128 consecutive per iter
    s += partials[(size_t)b * 128 + col];
    s += partials[(size_t)(b + 1) * 128 + col];
  }
  if (t >= 128) tmp[col] = s;
  __syncthreads();
  if (t < 128) tmp[t] = s + tmp[t];  // same-thread read->write, no race
  __syncthreads();
  if (t < 64) {
    const float sx = tmp[t], sxx = tmp[64 + t];
    const float invPN = 1.f / ((float)P * 64.f);
    const float mu = sx * invPN;
    const float var = sxx * invPN - mu * mu;
    const float a = gamma[t] * rsqrtf(var + EPS_);
    const float b = beta[t] - mu * a;
    shab[t] = make_float2(a, b);
    if (write_global) {
      abg[t] = a;
      abg[64 + t] = b;
    }
  }
  __syncthreads();
}

// kB: block 0 computes stats -> ab + flag; others overlap prologue, then
// spin (acquire) with a correct self-compute fallback. Then the proven
// MFMA main loop (A = masked bf16 feat rows, fused BN+relu+max epilogue).
__global__ __launch_bounds__(256, 4) void kB_mfma(
    const float* __restrict__ feats, const int* __restrict__ npts_arr,
    const int* __restrict__ coors, const float* __restrict__ W,
    const float* __restrict__ gamma, const float* __restrict__ beta,
    const float* __restrict__ partials, float* __restrict__ ab,
    unsigned int* __restrict__ flag, float* __restrict__ out, int P) {
  __shared__ float W_lds[576];
  __shared__ uint32_t A_lds[4][64][20];  // rows padded to 80 B
  __shared__ float2 shab[64];
  __shared__ float tmp[128];
  __shared__ int smode;
  const int t = threadIdx.x, lane = t & 63, wv = t >> 6;
  const int g16 = lane >> 4, l16 = lane & 15;

  for (int i = t; i < 576; i += 256) W_lds[i] = W[i];
  // zero the permanently-zero k-slots of this wave's A rows (once)
  A_lds[wv][lane][6] = 0u;
  A_lds[wv][lane][7] = 0u;
  *reinterpret_cast<uint4*>(&A_lds[wv][lane][8]) = make_uint4(0u, 0u, 0u, 0u);
  *reinterpret_cast<uint4*>(&A_lds[wv][lane][12]) = make_uint4(0u, 0u, 0u, 0u);
  __syncthreads();

  // B fragments from W_lds (LDS reads, trivial)
  uint4 bq[4];
#pragma unroll
  for (int nt = 0; nt < 4; ++nt) {
    const int col = nt * 16 + l16;
    ushort h[8];
#pragma unroll
    for (int j = 0; j < 8; ++j) {
      const int kk = 8 * g16 + j;
      h[j] = (kk < 9) ? bf16bits(W_lds[col * 9 + kk]) : (ushort)0;
    }
    bq[nt].x = (uint)h[0] | ((uint)h[1] << 16);
    bq[nt].y = (uint)h[2] | ((uint)h[3] << 16);
    bq[nt].z = (uint)h[4] | ((uint)h[5] << 16);
    bq[nt].w = (uint)h[6] | ((uint)h[7] << 16);
  }

  if (blockIdx.x == 0) {
    do_stats(partials, gamma, beta, ab, shab, tmp, P, t, true);
    if (t == 0) {
      __threadfence();  // make ab visible device-wide before the flag
      __hip_atomic_store(flag, MAGICF, __ATOMIC_RELEASE,
                         __HIP_MEMORY_SCOPE_AGENT);
    }
  } else {
    if (t == 0) {
      int got = 0;
      for (int it = 0; it < (1 << 13); ++it) {
        if (__hip_atomic_load(flag, __ATOMIC_ACQUIRE,
                              __HIP_MEMORY_SCOPE_AGENT) == MAGICF) {
          got = 1;
          break;
        }
        __builtin_amdgcn_s_sleep(8);
      }
      smode = got;
    }
    __syncthreads();
    if (smode) {  // normal path: ab ready in global
      if (t < 64) shab[t] = make_float2(ab[t], ab[64 + t]);
      __syncthreads();
    } else {  // fallback: self-compute identical reduction (correct, rare)
      do_stats(partials, gamma, beta, ab, shab, tmp, P, t, false);
    }
  }

  float ar[16], br[16];
#pragma unroll
  for (int i = 0; i < 16; ++i) {
    const int n = (i >> 2) * 16 + g16 * 4 + (i & 3);
    const float2 v = shab[n];
    ar[i] = v.x;
    br[i] = v.y;
  }

  const int stride = gridDim.x * 4;
  int p = blockIdx.x * 4 + wv;
  if (p >= P) return;
  float4 f = *reinterpret_cast<const float4*>(feats + (size_t)p * 256 + lane * 4);
  int np = npts_arr[p];
  int cx3 = coors[p * 4 + 3], cy2 = coors[p * 4 + 2];
  while (true) {
    const int p2 = p + stride;
    const bool has2 = p2 < P;
    float4 f2 = make_float4(0.f, 0.f, 0.f, 0.f);
    int np2 = 1, cx3b = 0, cy2b = 0;
    if (has2) {  // prefetch next pillar
      f2 = *reinterpret_cast<const float4*>(feats + (size_t)p2 * 256 + lane * 4);
      np2 = npts_arr[p2];
      cx3b = coors[p2 * 4 + 3];
      cy2b = coors[p2 * 4 + 2];
    }
    const float ox = (float)cx3 * VX_ + X_OFF_;
    const float oy = (float)cy2 * VY_ + Y_OFF_;
    const float inv = 1.f / (float)np;
    const float m0 = wave_sum(f.x) * inv;
    const float m1 = wave_sum(f.y) * inv;
    const float m2 = wave_sum(f.z) * inv;
    const bool valid = lane < np;
    const float c[9] = {f.x,      f.y,      f.z,      f.w,      f.x - m0,
                        f.y - m1, f.z - m2, f.x - ox, f.y - oy};
    union {
      ushort h[12];
      uint32_t u[6];
      uint4 q;
    } pk;
#pragma unroll
    for (int i = 0; i < 9; ++i) pk.h[i] = bf16bits(valid ? c[i] : 0.f);
    pk.h[9] = 0;
    pk.h[10] = 0;
    pk.h[11] = 0;
    // stage this lane's A row (lane == n); same-wave ds_write->ds_read is
    // in-order and each wave owns its A_lds[wv] region: no barrier needed.
    *reinterpret_cast<uint4*>(&A_lds[wv][lane][0]) = pk.q;
    *reinterpret_cast<uint2*>(&A_lds[wv][lane][4]) = make_uint2(pk.u[4], 0u);

    bf16x8 afr[4];
#pragma unroll
    for (int mt = 0; mt < 4; ++mt) {
      afr[mt] =
          *reinterpret_cast<const bf16x8*>(&A_lds[wv][mt * 16 + l16][g16 * 4]);
    }
    const f32x4 accz = {0.f, 0.f, 0.f, 0.f};
    float mx[4] = {0.f, 0.f, 0.f, 0.f};  // init 0 == fused relu
#pragma unroll
    for (int mt = 0; mt < 4; ++mt) {
      const bf16x8 a = afr[mt];
#pragma unroll
      for (int nt = 0; nt < 4; ++nt) {
        f32x4 acc4 = __builtin_amdgcn_mfma_f32_16x16x32_bf16(
            a, __builtin_bit_cast(bf16x8, bq[nt]), accz, 0, 0, 0);
#pragma unroll
        for (int r = 0; r < 4; ++r) {
          const float y = fmaf(acc4[r], ar[mt * 4 + r], br[mt * 4 + r]);
          mx[nt] = fmaxf(mx[nt], y);
        }
      }
    }
#pragma unroll
    for (int nt = 0; nt < 4; ++nt) {
      mx[nt] = fmaxf(mx[nt], __shfl_xor(mx[nt], 16));
      mx[nt] = fmaxf(mx[nt], __shfl_xor(mx[nt], 32));
    }
    const float outv =
        (g16 == 0) ? mx[0] : (g16 == 1) ? mx[1] : (g16 == 2) ? mx[2] : mx[3];
    out[(size_t)p * 64 + lane] = outv;  // o = g16*16 + l16 == lane
    if (!has2) break;
    p = p2;
    f = f2;
    np = np2;
    cx3 = cx3b;
    cy2 = cy2b;
  }
}

extern "C" void kernel_launch(void* const* d_in, const int* in_sizes, int n_in,
                              void* d_out, int out_size, void* d_ws,
                              size_t ws_size, hipStream_t stream) {
  const float* feats = (const float*)d_in[0];
  const int* npts = (const int*)d_in[1];
  const int* coors = (const int*)d_in[2];
  const float* W = (const float*)d_in[3];
  const float* gamma = (const float*)d_in[4];
  const float* beta = (const float*)d_in[5];
  float* out = (float*)d_out;
  float* ws = (float*)d_ws;

  const int P = in_sizes[1];  // num_points has P elements

  float* partials = ws;                               // [S1][128]
  float* ab = ws + S1 * 128;                          // [128]
  unsigned int* flag = (unsigned int*)(ws + S1 * 128 + 128);  // [1]

  kA_moments<<<S1, 256, 0, stream>>>(feats, npts, coors, W, partials, P);
  int nb = (P + 31) / 32;  // 4 waves/block, ~8 pillars/wave
  if (nb > 1024) nb = 1024;  // stay within guaranteed co-residency (4/CU)
  kB_mfma<<<nb, 256, 0, stream>>>(feats, npts, coors, W, gamma, beta, partials,
                                  ab, flag, out, P);
}

// Round 9
// 51.744 us; speedup vs baseline: 10.7902x; 10.7902x over previous
//
#include <hip/hip_runtime.h>
#include <hip/hip_bf16.h>
#include <math.h>

typedef __attribute__((ext_vector_type(8))) __bf16 bf16x8;
typedef __attribute__((ext_vector_type(4))) float f32x4;

constexpr float VX_ = 0.2f;
constexpr float VY_ = 0.2f;
constexpr float X_OFF_ = 0.1f;    // VX/2 + 0.0
constexpr float Y_OFF_ = -39.9f;  // VY/2 - 40.0
constexpr float EPS_ = 1e-3f;

#define S1 512  // kA block count; partials = [S1][128]

__device__ __forceinline__ float wave_sum(float v) {
#pragma unroll
  for (int off = 32; off; off >>= 1) v += __shfl_xor(v, off);
  return v;
}

__device__ __forceinline__ ushort bf16bits(float x) {
  __hip_bfloat16 h = __float2bfloat16(x);
  return __builtin_bit_cast(ushort, h);
}

// kA: inlined concurrent prep (W->LDS, G' = scaled W^T W + wsum) + per-n
// moments pre-contracted to 2 floats/thread. Block sums -> partials[b][t]
// (t<64: sum-x for n=t; t in 64..127: sum-x^2 for n=t-64). No atomics.
__global__ __launch_bounds__(256) void kA_moments(
    const float* __restrict__ feats, const int* __restrict__ npts_arr,
    const int* __restrict__ coors, const float* __restrict__ W,
    float* __restrict__ partials, int P) {
  __shared__ float W_lds[576];
  __shared__ float gws[54];  // G'[45] (off-diag doubled) + wsum[9]
  __shared__ float2 red[4][64];
  const int t = threadIdx.x, lane = t & 63, wv = t >> 6;

  for (int i = t; i < 576; i += 256) W_lds[i] = W[i];
  __syncthreads();
  if (t < 180) {  // G': 45 pairs x 4-way split over o
    const int pr = t >> 2, k = t & 3;
    int c = 0, rem = pr;
    while (rem >= 9 - c) {
      rem -= 9 - c;
      ++c;
    }
    const int c2 = c + rem;
    float s = 0.f;
    for (int o = k * 16; o < k * 16 + 16; ++o)
      s += W_lds[o * 9 + c] * W_lds[o * 9 + c2];
    s += __shfl_xor(s, 1);
    s += __shfl_xor(s, 2);
    if (k == 0) gws[pr] = (c == c2) ? s : 2.f * s;
  } else if (t < 216) {  // wsum: 9 cols x 4-way split
    const int tt = t - 180, c = tt >> 2, k = tt & 3;
    float s = 0.f;
    for (int o = k * 16; o < k * 16 + 16; ++o) s += W_lds[o * 9 + c];
    s += __shfl_xor(s, 1);
    s += __shfl_xor(s, 2);
    if (k == 0) gws[45 + c] = s;
  }
  __syncthreads();
  float g[45], wsv[9];
#pragma unroll
  for (int i = 0; i < 45; ++i) g[i] = gws[i];
#pragma unroll
  for (int i = 0; i < 9; ++i) wsv[i] = gws[45 + i];

  float s1 = 0.f, s2 = 0.f;
  const int nw = S1 * 4;
  int p = blockIdx.x * 4 + wv;
  if (p < P) {
    float4 f =
        *reinterpret_cast<const float4*>(feats + (size_t)p * 256 + lane * 4);
    int np = npts_arr[p];
    int cx = coors[p * 4 + 3], cy = coors[p * 4 + 2];
    while (true) {
      const int p2 = p + nw;
      const bool has2 = p2 < P;
      float4 f2 = make_float4(0.f, 0.f, 0.f, 0.f);
      int np2 = 1, cx2 = 0, cy2 = 0;
      if (has2) {  // prefetch next pillar
        f2 = *reinterpret_cast<const float4*>(feats + (size_t)p2 * 256 +
                                              lane * 4);
        np2 = npts_arr[p2];
        cx2 = coors[p2 * 4 + 3];
        cy2 = coors[p2 * 4 + 2];
      }
      const float ox = (float)cx * VX_ + X_OFF_;
      const float oy = (float)cy * VY_ + Y_OFF_;
      const float inv = 1.f / (float)np;
      const float m0 = wave_sum(f.x) * inv;
      const float m1 = wave_sum(f.y) * inv;
      const float m2 = wave_sum(f.z) * inv;
      const bool valid = lane < np;
      float ft[9] = {f.x,      f.y,      f.z,      f.w,      f.x - m0,
                     f.y - m1, f.z - m2, f.x - ox, f.y - oy};
#pragma unroll
      for (int c = 0; c < 9; ++c) ft[c] = valid ? ft[c] : 0.f;
      int idx = 0;
      float t1 = 0.f, t2 = 0.f;
#pragma unroll
      for (int c = 0; c < 9; ++c) {
        float u = 0.f;
#pragma unroll
        for (int c2 = c; c2 < 9; ++c2) u = fmaf(g[idx++], ft[c2], u);
        t2 = fmaf(ft[c], u, t2);
        t1 = fmaf(ft[c], wsv[c], t1);
      }
      s1 += t1;
      s2 += t2;
      if (!has2) break;
      p = p2;
      f = f2;
      np = np2;
      cx = cx2;
      cy = cy2;
    }
  }
  red[wv][lane] = make_float2(s1, s2);
  __syncthreads();
  if (t < 128) {
    const int n = t & 63, j = t >> 6;
    const float v = (j == 0)
                        ? (red[0][n].x + red[1][n].x + red[2][n].x + red[3][n].x)
                        : (red[0][n].y + red[1][n].y + red[2][n].y + red[3][n].y);
    partials[(size_t)blockIdx.x * 128 + t] = v;  // coalesced, non-atomic
  }
}

// kB: EVERY block independently recomputes the identical stats reduction
// (deterministic, same FP order everywhere -> identical a[n],b[n]; the
// 256 KB partials buffer is L2/L3-resident), then the proven MFMA loop:
// A = masked bf16 feat rows, fused BN + relu + max-over-n epilogue.
__global__ __launch_bounds__(256) void kB_mfma(
    const float* __restrict__ feats, const int* __restrict__ npts_arr,
    const int* __restrict__ coors, const float* __restrict__ W,
    const float* __restrict__ gamma, const float* __restrict__ beta,
    const float* __restrict__ partials, float* __restrict__ out, int P) {
  __shared__ float W_lds[576];
  __shared__ uint32_t A_lds[4][64][20];  // rows padded to 80 B
  __shared__ float2 shab[64];
  __shared__ float tmp[128];
  const int t = threadIdx.x, lane = t & 63, wv = t >> 6;
  const int g16 = lane >> 4, l16 = lane & 15;

  for (int i = t; i < 576; i += 256) W_lds[i] = W[i];
  // zero the permanently-zero k-slots of this wave's A rows (once)
  A_lds[wv][lane][6] = 0u;
  A_lds[wv][lane][7] = 0u;
  *reinterpret_cast<uint4*>(&A_lds[wv][lane][8]) = make_uint4(0u, 0u, 0u, 0u);
  *reinterpret_cast<uint4*>(&A_lds[wv][lane][12]) = make_uint4(0u, 0u, 0u, 0u);

  // ---- deterministic per-block stats recompute (no cross-block sync) ----
  {
    const int col = t & 127;
    const int base = (t >> 7) * (S1 / 2);
    float s0 = 0.f, s1 = 0.f;
    for (int b = base; b < base + S1 / 2; b += 2) {  // coalesced, L2-resident
      s0 += partials[(size_t)b * 128 + col];
      s1 += partials[(size_t)(b + 1) * 128 + col];
    }
    const float s = s0 + s1;
    if (t >= 128) tmp[col] = s;
    __syncthreads();
    if (t < 128) tmp[t] += s;  // own slot; written by partner thread above
    __syncthreads();
    if (t < 64) {
      const float sx = tmp[t], sxx = tmp[64 + t];
      const float invPN = 1.f / ((float)P * 64.f);
      const float mu = sx * invPN;
      const float var = sxx * invPN - mu * mu;
      const float a = gamma[t] * rsqrtf(var + EPS_);
      shab[t] = make_float2(a, beta[t] - mu * a);
    }
    __syncthreads();
  }

  // B fragments from W_lds
  uint4 bq[4];
#pragma unroll
  for (int nt = 0; nt < 4; ++nt) {
    const int col = nt * 16 + l16;
    ushort h[8];
#pragma unroll
    for (int j = 0; j < 8; ++j) {
      const int kk = 8 * g16 + j;
      h[j] = (kk < 9) ? bf16bits(W_lds[col * 9 + kk]) : (ushort)0;
    }
    bq[nt].x = (uint)h[0] | ((uint)h[1] << 16);
    bq[nt].y = (uint)h[2] | ((uint)h[3] << 16);
    bq[nt].z = (uint)h[4] | ((uint)h[5] << 16);
    bq[nt].w = (uint)h[6] | ((uint)h[7] << 16);
  }

  float ar[16], br[16];
#pragma unroll
  for (int i = 0; i < 16; ++i) {
    const int n = (i >> 2) * 16 + g16 * 4 + (i & 3);
    const float2 v = shab[n];
    ar[i] = v.x;
    br[i] = v.y;
  }

  const int stride = gridDim.x * 4;
  int p = blockIdx.x * 4 + wv;
  if (p >= P) return;
  float4 f = *reinterpret_cast<const float4*>(feats + (size_t)p * 256 + lane * 4);
  int np = npts_arr[p];
  int cx3 = coors[p * 4 + 3], cy2 = coors[p * 4 + 2];
  while (true) {
    const int p2 = p + stride;
    const bool has2 = p2 < P;
    float4 f2 = make_float4(0.f, 0.f, 0.f, 0.f);
    int np2 = 1, cx3b = 0, cy2b = 0;
    if (has2) {  // prefetch next pillar
      f2 = *reinterpret_cast<const float4*>(feats + (size_t)p2 * 256 + lane * 4);
      np2 = npts_arr[p2];
      cx3b = coors[p2 * 4 + 3];
      cy2b = coors[p2 * 4 + 2];
    }
    const float ox = (float)cx3 * VX_ + X_OFF_;
    const float oy = (float)cy2 * VY_ + Y_OFF_;
    const float inv = 1.f / (float)np;
    const float m0 = wave_sum(f.x) * inv;
    const float m1 = wave_sum(f.y) * inv;
    const float m2 = wave_sum(f.z) * inv;
    const bool valid = lane < np;
    const float c[9] = {f.x,      f.y,      f.z,      f.w,      f.x - m0,
                        f.y - m1, f.z - m2, f.x - ox, f.y - oy};
    union {
      ushort h[12];
      uint32_t u[6];
      uint4 q;
    } pk;
#pragma unroll
    for (int i = 0; i < 9; ++i) pk.h[i] = bf16bits(valid ? c[i] : 0.f);
    pk.h[9] = 0;
    pk.h[10] = 0;
    pk.h[11] = 0;
    // stage this lane's A row (lane == n); same-wave ds_write->ds_read is
    // in-order and each wave owns its A_lds[wv] region: no barrier needed.
    *reinterpret_cast<uint4*>(&A_lds[wv][lane][0]) = pk.q;
    *reinterpret_cast<uint2*>(&A_lds[wv][lane][4]) = make_uint2(pk.u[4], 0u);

    bf16x8 afr[4];
#pragma unroll
    for (int mt = 0; mt < 4; ++mt) {
      afr[mt] =
          *reinterpret_cast<const bf16x8*>(&A_lds[wv][mt * 16 + l16][g16 * 4]);
    }
    const f32x4 accz = {0.f, 0.f, 0.f, 0.f};
    float mx[4] = {0.f, 0.f, 0.f, 0.f};  // init 0 == fused relu
#pragma unroll
    for (int mt = 0; mt < 4; ++mt) {
      const bf16x8 a = afr[mt];
#pragma unroll
      for (int nt = 0; nt < 4; ++nt) {
        f32x4 acc4 = __builtin_amdgcn_mfma_f32_16x16x32_bf16(
            a, __builtin_bit_cast(bf16x8, bq[nt]), accz, 0, 0, 0);
#pragma unroll
        for (int r = 0; r < 4; ++r) {
          const float y = fmaf(acc4[r], ar[mt * 4 + r], br[mt * 4 + r]);
          mx[nt] = fmaxf(mx[nt], y);
        }
      }
    }
#pragma unroll
    for (int nt = 0; nt < 4; ++nt) {
      mx[nt] = fmaxf(mx[nt], __shfl_xor(mx[nt], 16));
      mx[nt] = fmaxf(mx[nt], __shfl_xor(mx[nt], 32));
    }
    const float outv =
        (g16 == 0) ? mx[0] : (g16 == 1) ? mx[1] : (g16 == 2) ? mx[2] : mx[3];
    out[(size_t)p * 64 + lane] = outv;  // o = g16*16 + l16 == lane
    if (!has2) break;
    p = p2;
    f = f2;
    np = np2;
    cx3 = cx3b;
    cy2 = cy2b;
  }
}

extern "C" void kernel_launch(void* const* d_in, const int* in_sizes, int n_in,
                              void* d_out, int out_size, void* d_ws,
                              size_t ws_size, hipStream_t stream) {
  const float* feats = (const float*)d_in[0];
  const int* npts = (const int*)d_in[1];
  const int* coors = (const int*)d_in[2];
  const float* W = (const float*)d_in[3];
  const float* gamma = (const float*)d_in[4];
  const float* beta = (const float*)d_in[5];
  float* out = (float*)d_out;
  float* partials = (float*)d_ws;  // [S1][128] floats

  const int P = in_sizes[1];  // num_points has P elements

  kA_moments<<<S1, 256, 0, stream>>>(feats, npts, coors, W, partials, P);
  const int nb = (P + 31) / 32;  // 4 waves/block, ~8 pillars/wave
  kB_mfma<<<nb, 256, 0, stream>>>(feats, npts, coors, W, gamma, beta, partials,
                                  out, P);
}

// Round 11
// 46.277 us; speedup vs baseline: 12.0648x; 1.1181x over previous
//
#include <hip/hip_runtime.h>
#include <hip/hip_bf16.h>
#include <math.h>

typedef __attribute__((ext_vector_type(8))) __bf16 bf16x8;
typedef __attribute__((ext_vector_type(4))) float f32x4;

constexpr float VX_ = 0.2f;
constexpr float VY_ = 0.2f;
constexpr float X_OFF_ = 0.1f;    // VX/2 + 0.0
constexpr float Y_OFF_ = -39.9f;  // VY/2 - 40.0
constexpr float EPS_ = 1e-3f;

__device__ __forceinline__ float wave_sum(float v) {
#pragma unroll
  for (int off = 32; off; off >>= 1) v += __shfl_xor(v, off);
  return v;
}

__device__ __forceinline__ ushort bf16bits(float x) {
  __hip_bfloat16 h = __float2bfloat16(x);
  return __builtin_bit_cast(ushort, h);
}

// packed RNE f32x2 -> bf16x2 (gfx950 has the instruction but no builtin)
__device__ __forceinline__ uint32_t cvtpk(float lo, float hi) {
  uint32_t r;
  asm("v_cvt_pk_bf16_f32 %0, %1, %2" : "=v"(r) : "v"(lo), "v"(hi));
  return r;
}

// k0 (one block): compute G' (scaled W^T W, off-diag doubled) + wsum and
// pre-pack the MFMA B fragments, so k1/k4 never rebuild them per block.
__global__ __launch_bounds__(256) void k0_prep(const float* __restrict__ W,
                                               float* __restrict__ gws,
                                               uint32_t* __restrict__ Bpack) {
  const int t = threadIdx.x;
  if (t < 180) {  // G': 45 pairs x 4-way split over o
    const int pr = t >> 2, k = t & 3;
    int c = 0, rem = pr;
    while (rem >= 9 - c) {
      rem -= 9 - c;
      ++c;
    }
    const int c2 = c + rem;
    float s = 0.f;
    for (int o = k * 16; o < k * 16 + 16; ++o) s += W[o * 9 + c] * W[o * 9 + c2];
    s += __shfl_xor(s, 1);
    s += __shfl_xor(s, 2);
    if (k == 0) gws[pr] = (c == c2) ? s : 2.f * s;
  } else if (t < 216) {  // wsum: 9 cols x 4-way split
    const int tt = t - 180, c = tt >> 2, k = tt & 3;
    float s = 0.f;
    for (int o = k * 16; o < k * 16 + 16; ++o) s += W[o * 9 + c];
    s += __shfl_xor(s, 1);
    s += __shfl_xor(s, 2);
    if (k == 0) gws[45 + c] = s;
  }
  {  // Bpack[t]: 8 bf16 = B fragment for (nt = t>>6, lane = t&63)
    const int nt = t >> 6, lane = t & 63;
    const int l16 = lane & 15, g16 = lane >> 4;
    const int col = nt * 16 + l16;
    ushort h[8];
#pragma unroll
    for (int j = 0; j < 8; ++j) {
      const int kk = 8 * g16 + j;
      h[j] = (kk < 9) ? bf16bits(W[col * 9 + kk]) : (ushort)0;
    }
    uint4 q;
    q.x = (uint)h[0] | ((uint)h[1] << 16);
    q.y = (uint)h[2] | ((uint)h[3] << 16);
    q.z = (uint)h[4] | ((uint)h[5] << 16);
    q.w = (uint)h[6] | ((uint)h[7] << 16);
    *reinterpret_cast<uint4*>(Bpack + (size_t)t * 4) = q;
  }
}

// k1: per-n sums of x and x^2, pre-contracted with G'/wsum (2-float
// accumulator per thread). Writes per-block partials (coalesced layout,
// NO atomics). partials layout: [(n*2 + j) * S + block].
__global__ __launch_bounds__(256) void k1_moments(
    const float* __restrict__ feats, const int* __restrict__ npts_arr,
    const int* __restrict__ coors, const float* __restrict__ gwsbuf,
    float* __restrict__ partials, int S, int P) {
  __shared__ float2 red[4][64];
  const int t = threadIdx.x, lane = t & 63, wv = t >> 6;
  float g[45], wsv[9];
#pragma unroll
  for (int i = 0; i < 45; ++i) g[i] = gwsbuf[i];  // uniform -> scalar loads
#pragma unroll
  for (int i = 0; i < 9; ++i) wsv[i] = gwsbuf[45 + i];

  float s1 = 0.f, s2 = 0.f;
  const int nw = S * 4;
  int p = blockIdx.x * 4 + wv;
  if (p < P) {
    float4 f =
        *reinterpret_cast<const float4*>(feats + (size_t)p * 256 + lane * 4);
    int np = npts_arr[p];
    int cx = coors[p * 4 + 3], cy = coors[p * 4 + 2];
    while (true) {
      const int p2 = p + nw;
      const bool has2 = p2 < P;
      float4 f2 = make_float4(0.f, 0.f, 0.f, 0.f);
      int np2 = 1, cx2 = 0, cy2 = 0;
      if (has2) {  // prefetch next pillar
        f2 = *reinterpret_cast<const float4*>(feats + (size_t)p2 * 256 +
                                              lane * 4);
        np2 = npts_arr[p2];
        cx2 = coors[p2 * 4 + 3];
        cy2 = coors[p2 * 4 + 2];
      }
      const float ox = (float)cx * VX_ + X_OFF_;
      const float oy = (float)cy * VY_ + Y_OFF_;
      const float inv = 1.f / (float)np;
      const float m0 = wave_sum(f.x) * inv;
      const float m1 = wave_sum(f.y) * inv;
      const float m2 = wave_sum(f.z) * inv;
      const bool valid = lane < np;
      float ft[9] = {f.x,      f.y,      f.z,      f.w,      f.x - m0,
                     f.y - m1, f.z - m2, f.x - ox, f.y - oy};
#pragma unroll
      for (int c = 0; c < 9; ++c) ft[c] = valid ? ft[c] : 0.f;
      int idx = 0;
      float t1 = 0.f, t2 = 0.f;
#pragma unroll
      for (int c = 0; c < 9; ++c) {
        float u = 0.f;
#pragma unroll
        for (int c2 = c; c2 < 9; ++c2) u = fmaf(g[idx++], ft[c2], u);
        t2 = fmaf(ft[c], u, t2);
        t1 = fmaf(ft[c], wsv[c], t1);
      }
      s1 += t1;
      s2 += t2;
      if (!has2) break;
      p = p2;
      f = f2;
      np = np2;
      cx = cx2;
      cy = cy2;
    }
  }
  red[wv][lane] = make_float2(s1, s2);
  __syncthreads();
  if (t < 64) {
    const float v = red[0][t].x + red[1][t].x + red[2][t].x + red[3][t].x;
    partials[((size_t)t * 2 + 0) * S + blockIdx.x] = v;
  } else if (t < 128) {
    const int n = t - 64;
    const float v = red[0][n].y + red[1][n].y + red[2][n].y + red[3][n].y;
    partials[((size_t)n * 2 + 1) * S + blockIdx.x] = v;
  }
}

// k2: reduce partials (coalesced), compute a[n], b[n]. One block per n.
__global__ __launch_bounds__(256) void k2_stats(
    const float* __restrict__ partials, const float* __restrict__ gamma,
    const float* __restrict__ beta, float* __restrict__ ab, int S, int P) {
  const int n = blockIdx.x, t = threadIdx.x;
  __shared__ float r1[4], r2[4];
  const float* p1 = partials + ((size_t)n * 2 + 0) * S;
  const float* p2 = partials + ((size_t)n * 2 + 1) * S;
  float a1 = 0.f, a2 = 0.f;
  for (int b = t; b < S; b += 256) {
    a1 += p1[b];
    a2 += p2[b];
  }
  a1 = wave_sum(a1);
  a2 = wave_sum(a2);
  const int wv = t >> 6;
  if ((t & 63) == 0) {
    r1[wv] = a1;
    r2[wv] = a2;
  }
  __syncthreads();
  if (t == 0) {
    const float v2 = r1[0] + r1[1] + r1[2] + r1[3];  // sum x
    const float v1 = r2[0] + r2[1] + r2[2] + r2[3];  // sum x^2
    const float invPN = 1.f / ((float)P * 64.f);
    const float mu = v2 * invPN;
    const float var = v1 * invPN - mu * mu;
    const float a = gamma[n] * rsqrtf(var + EPS_);
    const float b = beta[n] - mu * a;
    ab[n] = a;
    ab[64 + n] = b;
  }
}

// k4: main output via MFMA. B fragments from Bpack (coalesced), BN consts
// from ab. A = masked 9-ch feat rows (bf16, K padded to 32); masked rows
// zero => y = relu(b[n]) flows through the epilogue naturally.
// R11 edits vs proven R7: (1) v_cvt_pk_bf16_f32 packing (5 ops vs ~40),
// (2) invtab[np] LDS broadcast instead of per-pillar fdiv.
__global__ __launch_bounds__(256) void k4_mfma(
    const float* __restrict__ feats, const int* __restrict__ npts_arr,
    const int* __restrict__ coors, const uint32_t* __restrict__ Bpack,
    const float* __restrict__ ab, float* __restrict__ out, int P) {
  __shared__ uint32_t A_lds[4][64][20];  // rows padded to 80 B
  __shared__ float2 shab[64];
  __shared__ float invtab[65];
  const int t = threadIdx.x, lane = t & 63, wv = t >> 6;
  const int g16 = lane >> 4, l16 = lane & 15;
  if (t < 64) shab[t] = make_float2(ab[t], ab[64 + t]);
  if (t < 65) invtab[t] = 1.f / (float)t;  // t=0 unused (np >= 1)

  uint4 bq[4];
#pragma unroll
  for (int nt = 0; nt < 4; ++nt)
    bq[nt] =
        *reinterpret_cast<const uint4*>(Bpack + ((size_t)nt * 64 + lane) * 4);

  // zero the permanently-zero k-slots 6..15 of this wave's rows (once)
  A_lds[wv][lane][6] = 0u;
  A_lds[wv][lane][7] = 0u;
  *reinterpret_cast<uint4*>(&A_lds[wv][lane][8]) = make_uint4(0u, 0u, 0u, 0u);
  *reinterpret_cast<uint4*>(&A_lds[wv][lane][12]) = make_uint4(0u, 0u, 0u, 0u);
  __syncthreads();

  float ar[16], br[16];
#pragma unroll
  for (int i = 0; i < 16; ++i) {
    const int n = (i >> 2) * 16 + g16 * 4 + (i & 3);
    const float2 v = shab[n];
    ar[i] = v.x;
    br[i] = v.y;
  }

  const int stride = gridDim.x * 4;
  int p = blockIdx.x * 4 + wv;
  if (p >= P) return;
  float4 f = *reinterpret_cast<const float4*>(feats + (size_t)p * 256 + lane * 4);
  int np = npts_arr[p];
  int cx3 = coors[p * 4 + 3], cy2 = coors[p * 4 + 2];
  while (true) {
    const int p2 = p + stride;
    const bool has2 = p2 < P;
    float4 f2 = make_float4(0.f, 0.f, 0.f, 0.f);
    int np2 = 1, cx3b = 0, cy2b = 0;
    if (has2) {  // prefetch next pillar
      f2 = *reinterpret_cast<const float4*>(feats + (size_t)p2 * 256 + lane * 4);
      np2 = npts_arr[p2];
      cx3b = coors[p2 * 4 + 3];
      cy2b = coors[p2 * 4 + 2];
    }
    const float ox = (float)cx3 * VX_ + X_OFF_;
    const float oy = (float)cy2 * VY_ + Y_OFF_;
    const float inv = invtab[np];  // wave-uniform addr -> LDS broadcast
    const float m0 = wave_sum(f.x) * inv;
    const float m1 = wave_sum(f.y) * inv;
    const float m2 = wave_sum(f.z) * inv;
    const bool valid = lane < np;
    const float v0 = valid ? f.x : 0.f;
    const float v1 = valid ? f.y : 0.f;
    const float v2 = valid ? f.z : 0.f;
    const float v3 = valid ? f.w : 0.f;
    const float v4 = valid ? f.x - m0 : 0.f;
    const float v5 = valid ? f.y - m1 : 0.f;
    const float v6 = valid ? f.z - m2 : 0.f;
    const float v7 = valid ? f.x - ox : 0.f;
    const float v8 = valid ? f.y - oy : 0.f;
    union {
      uint32_t u[6];
      uint4 q;
    } pk;
    pk.u[0] = cvtpk(v0, v1);
    pk.u[1] = cvtpk(v2, v3);
    pk.u[2] = cvtpk(v4, v5);
    pk.u[3] = cvtpk(v6, v7);
    pk.u[4] = cvtpk(v8, 0.f);
    // stage this lane's A row (lane == n); same-wave ds_write->ds_read is
    // in-order and each wave owns its A_lds[wv] region: no barrier needed.
    *reinterpret_cast<uint4*>(&A_lds[wv][lane][0]) = pk.q;
    *reinterpret_cast<uint2*>(&A_lds[wv][lane][4]) = make_uint2(pk.u[4], 0u);

    bf16x8 afr[4];
#pragma unroll
    for (int mt = 0; mt < 4; ++mt) {
      afr[mt] =
          *reinterpret_cast<const bf16x8*>(&A_lds[wv][mt * 16 + l16][g16 * 4]);
    }
    const f32x4 accz = {0.f, 0.f, 0.f, 0.f};
    float mx[4] = {0.f, 0.f, 0.f, 0.f};  // init 0 == fused relu
#pragma unroll
    for (int mt = 0; mt < 4; ++mt) {
      const bf16x8 a = afr[mt];
#pragma unroll
      for (int nt = 0; nt < 4; ++nt) {
        f32x4 acc4 = __builtin_amdgcn_mfma_f32_16x16x32_bf16(
            a, __builtin_bit_cast(bf16x8, bq[nt]), accz, 0, 0, 0);
#pragma unroll
        for (int r = 0; r < 4; ++r) {
          const float y = fmaf(acc4[r], ar[mt * 4 + r], br[mt * 4 + r]);
          mx[nt] = fmaxf(mx[nt], y);
        }
      }
    }
#pragma unroll
    for (int nt = 0; nt < 4; ++nt) {
      mx[nt] = fmaxf(mx[nt], __shfl_xor(mx[nt], 16));
      mx[nt] = fmaxf(mx[nt], __shfl_xor(mx[nt], 32));
    }
    const float outv =
        (g16 == 0) ? mx[0] : (g16 == 1) ? mx[1] : (g16 == 2) ? mx[2] : mx[3];
    out[(size_t)p * 64 + lane] = outv;  // o = g16*16 + l16 == lane
    if (!has2) break;
    p = p2;
    f = f2;
    np = np2;
    cx3 = cx3b;
    cy2 = cy2b;
  }
}

extern "C" void kernel_launch(void* const* d_in, const int* in_sizes, int n_in,
                              void* d_out, int out_size, void* d_ws,
                              size_t ws_size, hipStream_t stream) {
  const float* feats = (const float*)d_in[0];
  const int* npts = (const int*)d_in[1];
  const int* coors = (const int*)d_in[2];
  const float* W = (const float*)d_in[3];
  const float* gamma = (const float*)d_in[4];
  const float* beta = (const float*)d_in[5];
  float* out = (float*)d_out;
  float* ws = (float*)d_ws;

  const int P = in_sizes[1];  // num_points has P elements

  float* gws = ws;                           // [54] G' + wsum (pad to 64)
  uint32_t* Bpack = (uint32_t*)(ws + 64);    // [1024] u32 = 4x64 uint4 frags
  float* ab = ws + 64 + 1024;                // [128]: a[64], b[64]
  float* partials = ws + 64 + 1024 + 128;    // [64][2][S]

  int S = 2048;
  while (S > 1 && (size_t)(64 * 2 * S + 1216) * 4 > ws_size) S >>= 1;

  k0_prep<<<1, 256, 0, stream>>>(W, gws, Bpack);
  k1_moments<<<S, 256, 0, stream>>>(feats, npts, coors, gws, partials, S, P);
  k2_stats<<<64, 256, 0, stream>>>(partials, gamma, beta, ab, S, P);
  const int g4 = (P + 15) / 16;  // 4 waves/block, ~4 pillars/wave
  k4_mfma<<<g4, 256, 0, stream>>>(feats, npts, coors, Bpack, ab, out, P);
}

// Round 12
// 44.145 us; speedup vs baseline: 12.6477x; 1.0483x over previous
//
#include <hip/hip_runtime.h>
#include <hip/hip_bf16.h>
#include <math.h>

typedef __attribute__((ext_vector_type(8))) __bf16 bf16x8;
typedef __attribute__((ext_vector_type(4))) float f32x4;

constexpr float VX_ = 0.2f;
constexpr float VY_ = 0.2f;
constexpr float X_OFF_ = 0.1f;    // VX/2 + 0.0
constexpr float Y_OFF_ = -39.9f;  // VY/2 - 40.0
constexpr float EPS_ = 1e-3f;

__device__ __forceinline__ float wave_sum(float v) {
#pragma unroll
  for (int off = 32; off; off >>= 1) v += __shfl_xor(v, off);
  return v;
}

__device__ __forceinline__ ushort bf16bits(float x) {
  __hip_bfloat16 h = __float2bfloat16(x);
  return __builtin_bit_cast(ushort, h);
}

// packed RNE f32x2 -> bf16x2 (gfx950 has the instruction but no builtin)
__device__ __forceinline__ uint32_t cvtpk(float lo, float hi) {
  uint32_t r;
  asm("v_cvt_pk_bf16_f32 %0, %1, %2" : "=v"(r) : "v"(lo), "v"(hi));
  return r;
}

// k0 (one block): compute G' (scaled W^T W, off-diag doubled) + wsum and
// pre-pack the MFMA B fragments, so k1/k4 never rebuild them per block.
__global__ __launch_bounds__(256) void k0_prep(const float* __restrict__ W,
                                               float* __restrict__ gws,
                                               uint32_t* __restrict__ Bpack) {
  const int t = threadIdx.x;
  if (t < 180) {  // G': 45 pairs x 4-way split over o
    const int pr = t >> 2, k = t & 3;
    int c = 0, rem = pr;
    while (rem >= 9 - c) {
      rem -= 9 - c;
      ++c;
    }
    const int c2 = c + rem;
    float s = 0.f;
    for (int o = k * 16; o < k * 16 + 16; ++o) s += W[o * 9 + c] * W[o * 9 + c2];
    s += __shfl_xor(s, 1);
    s += __shfl_xor(s, 2);
    if (k == 0) gws[pr] = (c == c2) ? s : 2.f * s;
  } else if (t < 216) {  // wsum: 9 cols x 4-way split
    const int tt = t - 180, c = tt >> 2, k = tt & 3;
    float s = 0.f;
    for (int o = k * 16; o < k * 16 + 16; ++o) s += W[o * 9 + c];
    s += __shfl_xor(s, 1);
    s += __shfl_xor(s, 2);
    if (k == 0) gws[45 + c] = s;
  }
  {  // Bpack[t]: 8 bf16 = B fragment for (nt = t>>6, lane = t&63)
    const int nt = t >> 6, lane = t & 63;
    const int l16 = lane & 15, g16 = lane >> 4;
    const int col = nt * 16 + l16;
    ushort h[8];
#pragma unroll
    for (int j = 0; j < 8; ++j) {
      const int kk = 8 * g16 + j;
      h[j] = (kk < 9) ? bf16bits(W[col * 9 + kk]) : (ushort)0;
    }
    uint4 q;
    q.x = (uint)h[0] | ((uint)h[1] << 16);
    q.y = (uint)h[2] | ((uint)h[3] << 16);
    q.z = (uint)h[4] | ((uint)h[5] << 16);
    q.w = (uint)h[6] | ((uint)h[7] << 16);
    *reinterpret_cast<uint4*>(Bpack + (size_t)t * 4) = q;
  }
}

// k1: per-n sums of x and x^2, pre-contracted with G'/wsum (2-float
// accumulator per thread). ALSO stores per-pillar aux {m0,m1,m2,ox,oy,np}
// so k4 needs no wave_sum / npts / coors at all. partials layout:
// [(n*2 + j) * S + block].
__global__ __launch_bounds__(256) void k1_moments(
    const float* __restrict__ feats, const int* __restrict__ npts_arr,
    const int* __restrict__ coors, const float* __restrict__ gwsbuf,
    float* __restrict__ partials, float* __restrict__ aux, int S, int P) {
  __shared__ float2 red[4][64];
  const int t = threadIdx.x, lane = t & 63, wv = t >> 6;
  float g[45], wsv[9];
#pragma unroll
  for (int i = 0; i < 45; ++i) g[i] = gwsbuf[i];  // uniform -> scalar loads
#pragma unroll
  for (int i = 0; i < 9; ++i) wsv[i] = gwsbuf[45 + i];

  float s1 = 0.f, s2 = 0.f;
  const int nw = S * 4;
  int p = blockIdx.x * 4 + wv;
  if (p < P) {
    float4 f =
        *reinterpret_cast<const float4*>(feats + (size_t)p * 256 + lane * 4);
    int np = npts_arr[p];
    int cx = coors[p * 4 + 3], cy = coors[p * 4 + 2];
    while (true) {
      const int p2 = p + nw;
      const bool has2 = p2 < P;
      float4 f2 = make_float4(0.f, 0.f, 0.f, 0.f);
      int np2 = 1, cx2 = 0, cy2 = 0;
      if (has2) {  // prefetch next pillar
        f2 = *reinterpret_cast<const float4*>(feats + (size_t)p2 * 256 +
                                              lane * 4);
        np2 = npts_arr[p2];
        cx2 = coors[p2 * 4 + 3];
        cy2 = coors[p2 * 4 + 2];
      }
      const float ox = (float)cx * VX_ + X_OFF_;
      const float oy = (float)cy * VY_ + Y_OFF_;
      const float inv = 1.f / (float)np;
      const float m0 = wave_sum(f.x) * inv;
      const float m1 = wave_sum(f.y) * inv;
      const float m2 = wave_sum(f.z) * inv;
      if (lane == 0) {  // per-pillar aux for k4 (fire-and-forget stores)
        *reinterpret_cast<float4*>(aux + (size_t)p * 8) =
            make_float4(m0, m1, m2, ox);
        *reinterpret_cast<float4*>(aux + (size_t)p * 8 + 4) =
            make_float4(oy, __int_as_float(np), 0.f, 0.f);
      }
      const bool valid = lane < np;
      float ft[9] = {f.x,      f.y,      f.z,      f.w,      f.x - m0,
                     f.y - m1, f.z - m2, f.x - ox, f.y - oy};
#pragma unroll
      for (int c = 0; c < 9; ++c) ft[c] = valid ? ft[c] : 0.f;
      int idx = 0;
      float t1 = 0.f, t2 = 0.f;
#pragma unroll
      for (int c = 0; c < 9; ++c) {
        float u = 0.f;
#pragma unroll
        for (int c2 = c; c2 < 9; ++c2) u = fmaf(g[idx++], ft[c2], u);
        t2 = fmaf(ft[c], u, t2);
        t1 = fmaf(ft[c], wsv[c], t1);
      }
      s1 += t1;
      s2 += t2;
      if (!has2) break;
      p = p2;
      f = f2;
      np = np2;
      cx = cx2;
      cy = cy2;
    }
  }
  red[wv][lane] = make_float2(s1, s2);
  __syncthreads();
  if (t < 64) {
    const float v = red[0][t].x + red[1][t].x + red[2][t].x + red[3][t].x;
    partials[((size_t)t * 2 + 0) * S + blockIdx.x] = v;
  } else if (t < 128) {
    const int n = t - 64;
    const float v = red[0][n].y + red[1][n].y + red[2][n].y + red[3][n].y;
    partials[((size_t)n * 2 + 1) * S + blockIdx.x] = v;
  }
}

// k2: reduce partials (coalesced), compute a[n], b[n]. One block per n.
__global__ __launch_bounds__(256) void k2_stats(
    const float* __restrict__ partials, const float* __restrict__ gamma,
    const float* __restrict__ beta, float* __restrict__ ab, int S, int P) {
  const int n = blockIdx.x, t = threadIdx.x;
  __shared__ float r1[4], r2[4];
  const float* p1 = partials + ((size_t)n * 2 + 0) * S;
  const float* p2 = partials + ((size_t)n * 2 + 1) * S;
  float a1 = 0.f, a2 = 0.f;
  for (int b = t; b < S; b += 256) {
    a1 += p1[b];
    a2 += p2[b];
  }
  a1 = wave_sum(a1);
  a2 = wave_sum(a2);
  const int wv = t >> 6;
  if ((t & 63) == 0) {
    r1[wv] = a1;
    r2[wv] = a2;
  }
  __syncthreads();
  if (t == 0) {
    const float v2 = r1[0] + r1[1] + r1[2] + r1[3];  // sum x
    const float v1 = r2[0] + r2[1] + r2[2] + r2[3];  // sum x^2
    const float invPN = 1.f / ((float)P * 64.f);
    const float mu = v2 * invPN;
    const float var = v1 * invPN - mu * mu;
    const float a = gamma[n] * rsqrtf(var + EPS_);
    const float b = beta[n] - mu * a;
    ab[n] = a;
    ab[64 + n] = b;
  }
}

// k4: MFMA main loop. R12: NO wave_sum, NO invtab, NO npts/coors loads —
// per-pillar aux {m0,m1,m2,ox,oy,np} comes precomputed from k1 via 2
// prefetched broadcast loads. LDS ops/pillar drop 33 -> 14 (H-LDS test).
__global__ __launch_bounds__(256) void k4_mfma(
    const float* __restrict__ feats, const float* __restrict__ aux,
    const uint32_t* __restrict__ Bpack, const float* __restrict__ ab,
    float* __restrict__ out, int P) {
  __shared__ uint32_t A_lds[4][64][20];  // rows padded to 80 B
  __shared__ float2 shab[64];
  const int t = threadIdx.x, lane = t & 63, wv = t >> 6;
  const int g16 = lane >> 4, l16 = lane & 15;
  if (t < 64) shab[t] = make_float2(ab[t], ab[64 + t]);

  uint4 bq[4];
#pragma unroll
  for (int nt = 0; nt < 4; ++nt)
    bq[nt] =
        *reinterpret_cast<const uint4*>(Bpack + ((size_t)nt * 64 + lane) * 4);

  // zero the permanently-zero k-slots 6..15 of this wave's rows (once)
  A_lds[wv][lane][6] = 0u;
  A_lds[wv][lane][7] = 0u;
  *reinterpret_cast<uint4*>(&A_lds[wv][lane][8]) = make_uint4(0u, 0u, 0u, 0u);
  *reinterpret_cast<uint4*>(&A_lds[wv][lane][12]) = make_uint4(0u, 0u, 0u, 0u);
  __syncthreads();

  float ar[16], br[16];
#pragma unroll
  for (int i = 0; i < 16; ++i) {
    const int n = (i >> 2) * 16 + g16 * 4 + (i & 3);
    const float2 v = shab[n];
    ar[i] = v.x;
    br[i] = v.y;
  }

  const int stride = gridDim.x * 4;
  int p = blockIdx.x * 4 + wv;
  if (p >= P) return;
  float4 f = *reinterpret_cast<const float4*>(feats + (size_t)p * 256 + lane * 4);
  float4 a0 = *reinterpret_cast<const float4*>(aux + (size_t)p * 8);
  float4 a1 = *reinterpret_cast<const float4*>(aux + (size_t)p * 8 + 4);
  while (true) {
    const int p2 = p + stride;
    const bool has2 = p2 < P;
    float4 f2 = make_float4(0.f, 0.f, 0.f, 0.f);
    float4 a0b = make_float4(0.f, 0.f, 0.f, 0.f);
    float4 a1b = make_float4(0.f, 0.f, 0.f, 0.f);
    if (has2) {  // prefetch next pillar (feat row + aux)
      f2 = *reinterpret_cast<const float4*>(feats + (size_t)p2 * 256 + lane * 4);
      a0b = *reinterpret_cast<const float4*>(aux + (size_t)p2 * 8);
      a1b = *reinterpret_cast<const float4*>(aux + (size_t)p2 * 8 + 4);
    }
    const float m0 = a0.x, m1 = a0.y, m2 = a0.z, ox = a0.w, oy = a1.x;
    const int np = __float_as_int(a1.y);
    const bool valid = lane < np;
    const float v0 = valid ? f.x : 0.f;
    const float v1 = valid ? f.y : 0.f;
    const float v2 = valid ? f.z : 0.f;
    const float v3 = valid ? f.w : 0.f;
    const float v4 = valid ? f.x - m0 : 0.f;
    const float v5 = valid ? f.y - m1 : 0.f;
    const float v6 = valid ? f.z - m2 : 0.f;
    const float v7 = valid ? f.x - ox : 0.f;
    const float v8 = valid ? f.y - oy : 0.f;
    union {
      uint32_t u[6];
      uint4 q;
    } pk;
    pk.u[0] = cvtpk(v0, v1);
    pk.u[1] = cvtpk(v2, v3);
    pk.u[2] = cvtpk(v4, v5);
    pk.u[3] = cvtpk(v6, v7);
    pk.u[4] = cvtpk(v8, 0.f);
    // stage this lane's A row (lane == n); same-wave ds_write->ds_read is
    // in-order and each wave owns its A_lds[wv] region: no barrier needed.
    *reinterpret_cast<uint4*>(&A_lds[wv][lane][0]) = pk.q;
    *reinterpret_cast<uint2*>(&A_lds[wv][lane][4]) = make_uint2(pk.u[4], 0u);

    bf16x8 afr[4];
#pragma unroll
    for (int mt = 0; mt < 4; ++mt) {
      afr[mt] =
          *reinterpret_cast<const bf16x8*>(&A_lds[wv][mt * 16 + l16][g16 * 4]);
    }
    const f32x4 accz = {0.f, 0.f, 0.f, 0.f};
    float mx[4] = {0.f, 0.f, 0.f, 0.f};  // init 0 == fused relu
#pragma unroll
    for (int mt = 0; mt < 4; ++mt) {
      const bf16x8 a = afr[mt];
#pragma unroll
      for (int nt = 0; nt < 4; ++nt) {
        f32x4 acc4 = __builtin_amdgcn_mfma_f32_16x16x32_bf16(
            a, __builtin_bit_cast(bf16x8, bq[nt]), accz, 0, 0, 0);
#pragma unroll
        for (int r = 0; r < 4; ++r) {
          const float y = fmaf(acc4[r], ar[mt * 4 + r], br[mt * 4 + r]);
          mx[nt] = fmaxf(mx[nt], y);
        }
      }
    }
#pragma unroll
    for (int nt = 0; nt < 4; ++nt) {
      mx[nt] = fmaxf(mx[nt], __shfl_xor(mx[nt], 16));
      mx[nt] = fmaxf(mx[nt], __shfl_xor(mx[nt], 32));
    }
    const float outv =
        (g16 == 0) ? mx[0] : (g16 == 1) ? mx[1] : (g16 == 2) ? mx[2] : mx[3];
    out[(size_t)p * 64 + lane] = outv;  // o = g16*16 + l16 == lane
    if (!has2) break;
    p = p2;
    f = f2;
    a0 = a0b;
    a1 = a1b;
  }
}

extern "C" void kernel_launch(void* const* d_in, const int* in_sizes, int n_in,
                              void* d_out, int out_size, void* d_ws,
                              size_t ws_size, hipStream_t stream) {
  const float* feats = (const float*)d_in[0];
  const int* npts = (const int*)d_in[1];
  const int* coors = (const int*)d_in[2];
  const float* W = (const float*)d_in[3];
  const float* gamma = (const float*)d_in[4];
  const float* beta = (const float*)d_in[5];
  float* out = (float*)d_out;
  float* ws = (float*)d_ws;

  const int P = in_sizes[1];  // num_points has P elements

  float* gws = ws;                          // [64]  G' + wsum
  uint32_t* Bpack = (uint32_t*)(ws + 64);   // [1024] u32 = 4x64 uint4 frags
  float* ab = ws + 64 + 1024;               // [128]: a[64], b[64]
  float* aux = ws + 1216;                   // [8*P]: per-pillar aux
  float* partials = ws + 1216 + 8 * (size_t)P;  // [64][2][S]

  int S = 2048;
  while (S > 1 &&
         (size_t)(64 * 2 * (size_t)S + 1216 + 8 * (size_t)P) * 4 > ws_size)
    S >>= 1;

  k0_prep<<<1, 256, 0, stream>>>(W, gws, Bpack);
  k1_moments<<<S, 256, 0, stream>>>(feats, npts, coors, gws, partials, aux, S,
                                    P);
  k2_stats<<<64, 256, 0, stream>>>(partials, gamma, beta, ab, S, P);
  const int g4 = (P + 15) / 16;  // 4 waves/block, ~4 pillars/wave
  k4_mfma<<<g4, 256, 0, stream>>>(feats, aux, Bpack, ab, out, P);
}